// Round 1
// baseline (722.930 us; speedup 1.0000x reference)
//
#include <hip/hip_runtime.h>
#include <hip/hip_cooperative_groups.h>

namespace cg = cooperative_groups;

#define NSEQ 4096
#define EDIM 1024

// ws layout (float offsets)
#define OFF_PBX  0u          // partial Bx [4 q][64 chain][4096]   = 4 MB
#define OFF_HLOC 1048576u    // local scan h  [64 chain][4096]     = 1 MB
#define OFF_PINC 1310720u    // local scan P  [64 chain][4096]     = 1 MB
#define OFF_SUM  1572864u    // chunk summaries [64][16][2]        = 8 KB
#define OFF_HT   1574912u    // h transposed [4 b][4096 t][16 s]   = 1 MB

__device__ __forceinline__ void fma4(float4& a, float xv, const float4& b) {
    a.x = fmaf(xv, b.x, a.x);
    a.y = fmaf(xv, b.y, a.y);
    a.z = fmaf(xv, b.z, a.z);
    a.w = fmaf(xv, b.w, a.w);
}

// ---------------------------------------------------------------------------
// Fused cooperative kernel. 1024 blocks x 256 threads, 4 blocks/CU
// co-resident (LDS 34.8 KB x 4 = 139 KB <= 160; launch_bounds caps VGPR).
// Phase 1: partial Bx (k1, LDS pitch 68 + b128 vector LDS ops).
// Phase 2a: 16x-parallel chunked scan (1 element/thread, block = 256-step
//           chunk of one chain), writes h_loc/P_inc + chunk summary.
// Phase 2b: combine <=15 chunk summaries, apply prefix, write ht[b][t][s].
// Phase 3: y = h @ C (+ x*D slow path)  (k3).
// grid.sync() + __threadfence between phases (cross-XCD visibility).
// ---------------------------------------------------------------------------
__global__ __launch_bounds__(256, 4) void fused(
        const float* __restrict__ x, const float* __restrict__ A,
        const float* __restrict__ Bin, const float* __restrict__ C,
        const float* __restrict__ D, float* ws, float* __restrict__ out) {
    __shared__ __align__(16) float smem[2 * 64 * 68];   // 34.8 KB
    const int tid  = threadIdx.x;
    const int lane = tid & 63;
    const int wu   = __builtin_amdgcn_readfirstlane(tid) >> 6;  // wave id

    // ---------------- phase 1: partial Bx = x @ B_in (per e-quarter) -------
    for (int v = blockIdx.x; v < 1024; v += gridDim.x) {
        const int q  = v & 3;                 // e-quarter
        const int r0 = (v >> 2) * 64;         // row base
        const int b  = r0 >> 12;
        const int n0 = r0 & 4095;
        const int eq = q * 256;
        const float4* xf4 = (const float4*)x;
        const float4* Bf4 = (const float4*)Bin;

        float acc[16];
#pragma unroll
        for (int s = 0; s < 16; s++) acc[s] = 0.f;

        // prefetch + stage chunk 0: 64 rows x 64 e, pitch 68 (16B-aligned,
        // 2-way max bank aliasing on b128 = free)
        float4 pf[4];
#pragma unroll
        for (int k = 0; k < 4; k++) {
            int i = tid + 256 * k, row = i >> 4, cq = i & 15;
            pf[k] = xf4[(size_t)(r0 + row) * 256 + q * 64 + cq];
        }
#pragma unroll
        for (int k = 0; k < 4; k++) {
            int i = tid + 256 * k, row = i >> 4, cq = i & 15;
            *(float4*)&smem[row * 68 + cq * 4] = pf[k];
        }
        __syncthreads();

        for (int c = 0; c < 4; ++c) {
            if (c < 3) {
#pragma unroll
                for (int k = 0; k < 4; k++) {
                    int i = tid + 256 * k, row = i >> 4, cq = i & 15;
                    pf[k] = xf4[(size_t)(r0 + row) * 256 + q * 64 + (c + 1) * 16 + cq];
                }
            }
            const float* stg = &smem[(c & 1) * 4352];
#pragma unroll
            for (int jj = 0; jj < 4; ++jj) {
                // one ds_read_b128 replaces 4 ds_read_b32
                const float4 xq = *(const float4*)&stg[lane * 68 + wu * 16 + jj * 4];
                const float xs[4] = {xq.x, xq.y, xq.z, xq.w};
#pragma unroll
                for (int m = 0; m < 4; ++m) {
                    const int e = eq + c * 64 + wu * 16 + jj * 4 + m;  // wave-uniform
                    const float4 b0 = Bf4[e * 4 + 0];
                    const float4 b1 = Bf4[e * 4 + 1];
                    const float4 b2 = Bf4[e * 4 + 2];
                    const float4 b3 = Bf4[e * 4 + 3];
                    const float xv = xs[m];
                    acc[0]  = fmaf(xv, b0.x, acc[0]);  acc[1]  = fmaf(xv, b0.y, acc[1]);
                    acc[2]  = fmaf(xv, b0.z, acc[2]);  acc[3]  = fmaf(xv, b0.w, acc[3]);
                    acc[4]  = fmaf(xv, b1.x, acc[4]);  acc[5]  = fmaf(xv, b1.y, acc[5]);
                    acc[6]  = fmaf(xv, b1.z, acc[6]);  acc[7]  = fmaf(xv, b1.w, acc[7]);
                    acc[8]  = fmaf(xv, b2.x, acc[8]);  acc[9]  = fmaf(xv, b2.y, acc[9]);
                    acc[10] = fmaf(xv, b2.z, acc[10]); acc[11] = fmaf(xv, b2.w, acc[11]);
                    acc[12] = fmaf(xv, b3.x, acc[12]); acc[13] = fmaf(xv, b3.y, acc[13]);
                    acc[14] = fmaf(xv, b3.z, acc[14]); acc[15] = fmaf(xv, b3.w, acc[15]);
                }
            }
            if (c < 3) {
                float* dst = &smem[((c + 1) & 1) * 4352];
#pragma unroll
                for (int k = 0; k < 4; k++) {
                    int i = tid + 256 * k, row = i >> 4, cq = i & 15;
                    *(float4*)&dst[row * 68 + cq * 4] = pf[k];
                }
            }
            __syncthreads();
        }

        // cross-wave reduction: red[4 waves][64 rows][17] aliases buffer 0
        {
            const int rb = (wu * 64 + lane) * 17;
#pragma unroll
            for (int s = 0; s < 16; s++) smem[rb + s] = acc[s];
        }
        __syncthreads();

#pragma unroll
        for (int p = 0; p < 4; p++) {
            const int o   = tid + 256 * p;
            const int s   = o >> 6;      // wave-uniform
            const int row = o & 63;
            const float vv = smem[(0 * 64 + row) * 17 + s] + smem[(1 * 64 + row) * 17 + s] +
                             smem[(2 * 64 + row) * 17 + s] + smem[(3 * 64 + row) * 17 + s];
            ws[OFF_PBX + (size_t)q * 262144u + (size_t)(b * 16 + s) * NSEQ + n0 + row] = vv;
        }
        __syncthreads();   // smem reused by next task / next phase
    }

    __threadfence();
    cg::this_grid().sync();
    __threadfence();

    // ---------------- phase 2a: local chunk scans (16x parallel vs old k2) -
    // block = (chain, 256-step chunk); thread = 1 timestep (1 softplus+2 exp)
    for (int v = blockIdx.x; v < 1024; v += gridDim.x) {
        const int chain = v >> 4;
        const int chunk = v & 15;
        const int ss = chain & 15;
        const int t  = chunk * 256 + tid;
        const int w  = tid >> 6;

        float bxv = 0.f;
#pragma unroll
        for (int q = 0; q < 4; q++)
            bxv += ws[OFF_PBX + (size_t)q * 262144u + (size_t)chain * NSEQ + t];

        const float Ae = expf(A[ss]);
        const float sp = fmaxf(bxv, 0.f) + log1pf(expf(-fabsf(bxv)));
        const float de = expf(-Ae * sp);

        // wave-inclusive scan of (P,h) under h' = h_left*P_right + h_right
        float Pi = de, hi = bxv;
#pragma unroll
        for (int off = 1; off < 64; off <<= 1) {
            float Pp = __shfl_up(Pi, off, 64);
            float hp = __shfl_up(hi, off, 64);
            if (lane >= off) { hi = fmaf(hp, Pi, hi); Pi *= Pp; }
        }
        if (lane == 63) { smem[w] = Pi; smem[4 + w] = hi; }
        __syncthreads();
        float Pw = 1.f, Hw = 0.f;
        for (int qq = 0; qq < w; qq++) {
            Hw = fmaf(Hw, smem[qq], smem[4 + qq]);
            Pw *= smem[qq];
        }
        const float hloc = fmaf(Hw, Pi, hi);   // inclusive within chunk
        const float pinc = Pw * Pi;
        ws[OFF_HLOC + (size_t)chain * NSEQ + t] = hloc;
        ws[OFF_PINC + (size_t)chain * NSEQ + t] = pinc;
        if (tid == 255) {   // chunk summary
            ws[OFF_SUM + (chain * 16 + chunk) * 2 + 0] = pinc;
            ws[OFF_SUM + (chain * 16 + chunk) * 2 + 1] = hloc;
        }
        __syncthreads();
    }

    __threadfence();
    cg::this_grid().sync();
    __threadfence();

    // ---------------- phase 2b: apply cross-chunk prefix, write ht ---------
    for (int v = blockIdx.x; v < 1024; v += gridDim.x) {
        const int chain = v >> 4;
        const int chunk = v & 15;
        const int bb = chain >> 4, ss = chain & 15;
        const int t  = chunk * 256 + tid;
        float H = 0.f;                       // block-uniform, <=15 scalar FMAs
        for (int c = 0; c < chunk; ++c) {
            const float Pc = ws[OFF_SUM + (chain * 16 + c) * 2 + 0];
            const float hc = ws[OFF_SUM + (chain * 16 + c) * 2 + 1];
            H = fmaf(H, Pc, hc);
        }
        const float h = fmaf(ws[OFF_PINC + (size_t)chain * NSEQ + t], H,
                             ws[OFF_HLOC + (size_t)chain * NSEQ + t]);
        ws[OFF_HT + ((size_t)bb * NSEQ + t) * 16 + ss] = h;
    }

    __threadfence();
    cg::this_grid().sync();
    __threadfence();

    // ---------------- phase 3: y = h @ C + x * D ---------------------------
    const float4* C4 = (const float4*)C;  // [16][256] float4
    float4 creg[16];
#pragma unroll
    for (int s = 0; s < 16; s++) creg[s] = C4[s * 256 + tid];
    const float4 dreg = ((const float4*)D)[tid];
    const bool needX = __any((dreg.x != 0.f) | (dreg.y != 0.f) |
                             (dreg.z != 0.f) | (dreg.w != 0.f));
    const float4* x4 = (const float4*)x;
    float4* o4 = (float4*)out;

    for (int v = blockIdx.x; v < 1024; v += gridDim.x) {
        const int tc = v & 255;
        const int b  = v >> 8;
        const int t0 = tc * 16;
        const float* hb = ws + OFF_HT + ((size_t)b * NSEQ + t0) * 16;  // 16x16
        const size_t rowbase = ((size_t)b * NSEQ + t0) * 256;

        if (needX) {
#pragma unroll 4
            for (int tt = 0; tt < 16; tt++) {
                float4 xv = x4[rowbase + tt * 256 + tid];
                float4 y;
                y.x = xv.x * dreg.x; y.y = xv.y * dreg.y;
                y.z = xv.z * dreg.z; y.w = xv.w * dreg.w;
#pragma unroll
                for (int s = 0; s < 16; s++) fma4(y, hb[tt * 16 + s], creg[s]);
                o4[rowbase + tt * 256 + tid] = y;
            }
        } else {
#pragma unroll 4
            for (int tt = 0; tt < 16; tt++) {
                float4 y = make_float4(0.f, 0.f, 0.f, 0.f);
#pragma unroll
                for (int s = 0; s < 16; s++) fma4(y, hb[tt * 16 + s], creg[s]);
                o4[rowbase + tt * 256 + tid] = y;
            }
        }
    }
}

extern "C" void kernel_launch(void* const* d_in, const int* in_sizes, int n_in,
                              void* d_out, int out_size, void* d_ws, size_t ws_size,
                              hipStream_t stream) {
    const float* x   = (const float*)d_in[0];
    const float* A   = (const float*)d_in[1];
    const float* Bin = (const float*)d_in[2];
    const float* C   = (const float*)d_in[3];
    const float* D   = (const float*)d_in[4];
    float* out = (float*)d_out;
    float* ws  = (float*)d_ws;

    // Grid = co-resident capacity (expected 1024 = 4 blocks/CU x 256 CU);
    // task loops inside the kernel tolerate any smaller grid.
    static int grid = 0;
    if (grid == 0) {
        int maxb = 0;
        hipOccupancyMaxActiveBlocksPerMultiprocessor(&maxb, fused, 256, 0);
        hipDeviceProp_t prop;
        hipGetDeviceProperties(&prop, 0);
        int g = maxb * prop.multiProcessorCount;
        if (g > 1024) g = 1024;
        if (g < 1) g = 1;
        grid = g;
    }

    void* args[] = {(void*)&x, (void*)&A, (void*)&Bin, (void*)&C,
                    (void*)&D, (void*)&ws, (void*)&out};
    hipLaunchCooperativeKernel(fused, dim3(grid), dim3(256), args, 0, stream);
}

// Round 2
// 147.231 us; speedup vs baseline: 4.9102x; 4.9102x over previous
//
#include <hip/hip_runtime.h>

#define NSEQ 4096
#define EDIM 1024

// ws layout (float offsets)
#define OFF_PBX  0u          // partial Bx [4 q][64 chain][4096]   = 4 MB
#define OFF_HLOC 1048576u    // chunk-local scan h [64][4096]      = 1 MB
#define OFF_PINC 1310720u    // chunk-local scan P [64][4096]      = 1 MB
#define OFF_SUM  1572864u    // chunk summaries [64 chain][16][2]  = 8 KB

__device__ __forceinline__ void fma4(float4& a, float xv, const float4& b) {
    a.x = fmaf(xv, b.x, a.x);
    a.y = fmaf(xv, b.y, a.y);
    a.z = fmaf(xv, b.z, a.z);
    a.w = fmaf(xv, b.w, a.w);
}

// ---------------------------------------------------------------------------
// k1: partial Bx = x @ B_in over one e-quarter (256 e).
// 1024 blocks (256 row-groups x 4 quarters) x 256 threads -> 4 blocks/CU.
// lane = row; wave's 16-e slice is wave-uniform (B via s_load). x staged in
// double-buffered LDS chunks of 64 rows x 64 e, pitch 68 (16B-aligned;
// b128 lane-stride 68 floats -> <=2-way bank aliasing = free).
// ds_read_b128/ds_write_b128: 4x fewer LDS instrs than the b32 version.
// ---------------------------------------------------------------------------
__global__ __launch_bounds__(256, 4) void k1_bx(const float* __restrict__ x,
                                                const float* __restrict__ Bin,
                                                float* __restrict__ ws) {
    __shared__ __align__(16) float smem[2 * 64 * 68];   // 34.8 KB
    const int tid  = threadIdx.x;
    const int lane = tid & 63;                                  // row
    const int wu   = __builtin_amdgcn_readfirstlane(tid) >> 6;  // wave id
    const int q    = blockIdx.x & 3;                            // e-quarter
    const int r0   = (blockIdx.x >> 2) * 64;                    // row base
    const int b    = r0 >> 12;
    const int n0   = r0 & 4095;
    const int eq   = q * 256;

    const float4* xf4 = (const float4*)x;
    const float4* Bf4 = (const float4*)Bin;

    float acc[16];
#pragma unroll
    for (int s = 0; s < 16; s++) acc[s] = 0.f;

    // prefetch + stage chunk 0: 64 rows x 64 e = 1024 float4; 4 per thread
    float4 pf[4];
#pragma unroll
    for (int k = 0; k < 4; k++) {
        int i = tid + 256 * k, row = i >> 4, cq = i & 15;
        pf[k] = xf4[(size_t)(r0 + row) * 256 + q * 64 + cq];
    }
#pragma unroll
    for (int k = 0; k < 4; k++) {
        int i = tid + 256 * k, row = i >> 4, cq = i & 15;
        *(float4*)&smem[row * 68 + cq * 4] = pf[k];
    }
    __syncthreads();

    for (int c = 0; c < 4; ++c) {
        if (c < 3) {   // prefetch chunk c+1 into regs
#pragma unroll
            for (int k = 0; k < 4; k++) {
                int i = tid + 256 * k, row = i >> 4, cq = i & 15;
                pf[k] = xf4[(size_t)(r0 + row) * 256 + q * 64 + (c + 1) * 16 + cq];
            }
        }
        const float* stg = &smem[(c & 1) * 4352];
#pragma unroll
        for (int jj = 0; jj < 4; ++jj) {
            // one ds_read_b128 replaces 4 ds_read_b32
            const float4 xq = *(const float4*)&stg[lane * 68 + wu * 16 + jj * 4];
            const float xs[4] = {xq.x, xq.y, xq.z, xq.w};
#pragma unroll
            for (int m = 0; m < 4; ++m) {
                const int e = eq + c * 64 + wu * 16 + jj * 4 + m;  // wave-uniform
                const float4 b0 = Bf4[e * 4 + 0];
                const float4 b1 = Bf4[e * 4 + 1];
                const float4 b2 = Bf4[e * 4 + 2];
                const float4 b3 = Bf4[e * 4 + 3];
                const float xv = xs[m];
                acc[0]  = fmaf(xv, b0.x, acc[0]);  acc[1]  = fmaf(xv, b0.y, acc[1]);
                acc[2]  = fmaf(xv, b0.z, acc[2]);  acc[3]  = fmaf(xv, b0.w, acc[3]);
                acc[4]  = fmaf(xv, b1.x, acc[4]);  acc[5]  = fmaf(xv, b1.y, acc[5]);
                acc[6]  = fmaf(xv, b1.z, acc[6]);  acc[7]  = fmaf(xv, b1.w, acc[7]);
                acc[8]  = fmaf(xv, b2.x, acc[8]);  acc[9]  = fmaf(xv, b2.y, acc[9]);
                acc[10] = fmaf(xv, b2.z, acc[10]); acc[11] = fmaf(xv, b2.w, acc[11]);
                acc[12] = fmaf(xv, b3.x, acc[12]); acc[13] = fmaf(xv, b3.y, acc[13]);
                acc[14] = fmaf(xv, b3.z, acc[14]); acc[15] = fmaf(xv, b3.w, acc[15]);
            }
        }
        if (c < 3) {   // stage chunk c+1 into the other buffer
            float* dst = &smem[((c + 1) & 1) * 4352];
#pragma unroll
            for (int k = 0; k < 4; k++) {
                int i = tid + 256 * k, row = i >> 4, cq = i & 15;
                *(float4*)&dst[row * 68 + cq * 4] = pf[k];
            }
        }
        __syncthreads();
    }

    // cross-wave reduction: red[4 waves][64 rows][17] aliases the buffers
    {
        const int rb = (wu * 64 + lane) * 17;
#pragma unroll
        for (int s = 0; s < 16; s++) smem[rb + s] = acc[s];
    }
    __syncthreads();

#pragma unroll
    for (int p = 0; p < 4; p++) {
        const int o   = tid + 256 * p;
        const int s   = o >> 6;      // wave-uniform
        const int row = o & 63;
        const float v = smem[(0 * 64 + row) * 17 + s] + smem[(1 * 64 + row) * 17 + s] +
                        smem[(2 * 64 + row) * 17 + s] + smem[(3 * 64 + row) * 17 + s];
        ws[OFF_PBX + (size_t)q * 262144u + (size_t)(b * 16 + s) * NSEQ + n0 + row] = v;
    }
}

// ---------------------------------------------------------------------------
// k2: chunk-local scans, 16x more parallel than the old monolithic scan.
// 1024 blocks x 256 threads; block = (chain, 256-step chunk); thread = one
// timestep (sum 4 partial-Bx quarters, softplus, exp). Wave-inclusive scan
// + 4-wave LDS combine (1 barrier). Writes hloc/pinc + chunk summary; the
// cross-chunk prefix is folded into k3 (dispatch boundary = free barrier).
// ---------------------------------------------------------------------------
__global__ __launch_bounds__(256) void k2_scan(const float* __restrict__ A,
                                               float* __restrict__ ws) {
    __shared__ float sP[4], sH[4];
    const int tid   = threadIdx.x;
    const int lane  = tid & 63;
    const int w     = tid >> 6;
    const int chain = blockIdx.x >> 4;
    const int chunk = blockIdx.x & 15;
    const int ss    = chain & 15;
    const int t     = chunk * 256 + tid;

    float bxv = 0.f;
#pragma unroll
    for (int q = 0; q < 4; q++)
        bxv += ws[OFF_PBX + (size_t)q * 262144u + (size_t)chain * NSEQ + t];

    const float Ae = expf(A[ss]);
    const float sp = fmaxf(bxv, 0.f) + log1pf(expf(-fabsf(bxv)));
    const float de = expf(-Ae * sp);

    // wave-inclusive scan of (P,h) under combine h' = h_left*P_right + h_right
    float Pi = de, hi = bxv;
#pragma unroll
    for (int off = 1; off < 64; off <<= 1) {
        float Pp = __shfl_up(Pi, off, 64);
        float hp = __shfl_up(hi, off, 64);
        if (lane >= off) { hi = fmaf(hp, Pi, hi); Pi *= Pp; }
    }
    if (lane == 63) { sP[w] = Pi; sH[w] = hi; }
    __syncthreads();
    float Hw = 0.f, Pw = 1.f;
    for (int qq = 0; qq < w; qq++) { Hw = fmaf(Hw, sP[qq], sH[qq]); Pw *= sP[qq]; }

    const float hloc = fmaf(Hw, Pi, hi);   // inclusive within chunk
    const float pinc = Pw * Pi;
    ws[OFF_HLOC + (size_t)chain * NSEQ + t] = hloc;
    ws[OFF_PINC + (size_t)chain * NSEQ + t] = pinc;
    if (tid == 255) {
        ws[OFF_SUM + (chain * 16 + chunk) * 2 + 0] = pinc;
        ws[OFF_SUM + (chain * 16 + chunk) * 2 + 1] = hloc;
    }
}

// ---------------------------------------------------------------------------
// k3: reconstruct h from (hloc, pinc, summaries) into a 16x17 LDS tile, then
// y[b,t,e] = sum_s h[t,s]*C[s,e] + x*D. 1024 blocks x 256 threads; each block
// covers 16 t of one batch. C columns in VGPRs; h via LDS broadcast reads.
// D == 0 fast path skips the x read (slow path kept correct).
// ---------------------------------------------------------------------------
__global__ __launch_bounds__(256) void k3_out(const float* __restrict__ x,
                                              const float* __restrict__ C,
                                              const float* __restrict__ D,
                                              const float* __restrict__ ws,
                                              float* __restrict__ out) {
    __shared__ float sh[16 * 17];
    const int tid = threadIdx.x;
    const int blk = blockIdx.x;
    const int tc  = blk & 255;
    const int b   = blk >> 8;
    const int t0  = tc * 16;
    const int chunk = t0 >> 8;        // all 16 t's live in this 256-chunk

    // reconstruct h[tt][s]: thread (s = tid>>4, tt = tid&15)
    {
        const int s  = tid >> 4;
        const int tt = tid & 15;
        const int chain = b * 16 + s;
        float H = 0.f;                // scan state entering this chunk
        for (int c = 0; c < chunk; ++c) {
            const float Pc = ws[OFF_SUM + (chain * 16 + c) * 2 + 0];
            const float hc = ws[OFF_SUM + (chain * 16 + c) * 2 + 1];
            H = fmaf(H, Pc, hc);
        }
        const int t = t0 + tt;
        const float h = fmaf(ws[OFF_PINC + (size_t)chain * NSEQ + t], H,
                             ws[OFF_HLOC + (size_t)chain * NSEQ + t]);
        sh[tt * 17 + s] = h;
    }

    const float4* C4 = (const float4*)C;  // [16][256] float4
    float4 creg[16];
#pragma unroll
    for (int s = 0; s < 16; s++) creg[s] = C4[s * 256 + tid];
    const float4 dreg = ((const float4*)D)[tid];
    const bool needX = __any((dreg.x != 0.f) | (dreg.y != 0.f) |
                             (dreg.z != 0.f) | (dreg.w != 0.f));
    __syncthreads();

    const float4* x4 = (const float4*)x;
    float4* o4 = (float4*)out;
    const size_t rowbase = ((size_t)b * NSEQ + t0) * 256;

    if (needX) {
#pragma unroll 4
        for (int tt = 0; tt < 16; tt++) {
            float4 xv = x4[rowbase + tt * 256 + tid];
            float4 y;
            y.x = xv.x * dreg.x; y.y = xv.y * dreg.y;
            y.z = xv.z * dreg.z; y.w = xv.w * dreg.w;
#pragma unroll
            for (int s = 0; s < 16; s++) fma4(y, sh[tt * 17 + s], creg[s]);
            o4[rowbase + tt * 256 + tid] = y;
        }
    } else {
#pragma unroll 4
        for (int tt = 0; tt < 16; tt++) {
            float4 y = make_float4(0.f, 0.f, 0.f, 0.f);
#pragma unroll
            for (int s = 0; s < 16; s++) fma4(y, sh[tt * 17 + s], creg[s]);
            o4[rowbase + tt * 256 + tid] = y;
        }
    }
}

extern "C" void kernel_launch(void* const* d_in, const int* in_sizes, int n_in,
                              void* d_out, int out_size, void* d_ws, size_t ws_size,
                              hipStream_t stream) {
    const float* x   = (const float*)d_in[0];
    const float* A   = (const float*)d_in[1];
    const float* Bin = (const float*)d_in[2];
    const float* C   = (const float*)d_in[3];
    const float* D   = (const float*)d_in[4];
    float* out = (float*)d_out;
    float* ws  = (float*)d_ws;

    hipLaunchKernelGGL(k1_bx,   dim3(1024), dim3(256), 0, stream, x, Bin, ws);
    hipLaunchKernelGGL(k2_scan, dim3(1024), dim3(256), 0, stream, A, ws);
    hipLaunchKernelGGL(k3_out,  dim3(1024), dim3(256), 0, stream, x, C, D, ws, out);
}